// Round 5
// baseline (241.764 us; speedup 1.0000x reference)
//
#include <hip/hip_runtime.h>

#define EPS_ 1e-5f
#define BATCH 32
#define CIN 240
#define H_ 56
#define W_ 56
#define HW 3136          // 56*56
#define C1 24            // init_c
#define R_ 9             // ratio-1
#define C2 216           // C1*R_
#define COUT 240

// ---- workspace layout (floats) ---- total 6464 floats (~26 KB)
#define WS_WT   0        // [240][24]  conv1x1 weights, ci-major, BN1 scale folded
#define WS_B1   5760     // [24]       BN1 bias
#define WS_WDW  5784     // [24][9]    dw weights, BN2 scale folded
#define WS_B2   6000     // [24]       BN2 bias
#define WS_INV3 6024     // [216]
#define WS_T3   6240     // [216]
// t1 (conv1x1+BN1 intermediate) lives in OUT channels [24,48) until the adder
// kernel overwrites them (stream-ordered; every kernel's read set is disjoint
// from its own write set).

__global__ __launch_bounds__(256) void prep_kernel(
    const float* __restrict__ wp,
    const float* __restrict__ g1, const float* __restrict__ b1,
    const float* __restrict__ m1, const float* __restrict__ v1,
    const float* __restrict__ wdw,
    const float* __restrict__ g2, const float* __restrict__ b2,
    const float* __restrict__ m2, const float* __restrict__ v2,
    const float* __restrict__ g3, const float* __restrict__ b3,
    const float* __restrict__ m3, const float* __restrict__ v3,
    float* __restrict__ ws) {
  int i = blockIdx.x * 256 + threadIdx.x;
  if (i < 5760) {
    // transpose w_primary (co-major [24][240]) -> ci-major [240][24], fold BN1
    int ci = i / C1, co = i % C1;
    float s = g1[co] / sqrtf(v1[co] + EPS_);
    ws[WS_WT + ci * C1 + co] = wp[co * CIN + ci] * s;
    if (ci == 0) ws[WS_B1 + co] = b1[co] - m1[co] * s;
  } else if (i < 5760 + C2) {
    int j = i - 5760;           // [0,216): c*9+k
    int c = j / 9;
    float s = g2[c] / sqrtf(v2[c] + EPS_);
    ws[WS_WDW + j] = wdw[j] * s;
    if (j % 9 == 0) ws[WS_B2 + c] = b2[c] - m2[c] * s;
  } else if (i < 5976 + C2) {
    int j = i - 5976;           // [0,216)
    float s = g3[j] / sqrtf(v3[j] + EPS_);
    ws[WS_INV3 + j] = s;
    ws[WS_T3 + j] = b3[j] - m3[j] * s;
  }
}

// 1x1 conv (240 -> 24) + BN1 -> out channels [24,48).
// Block = 512 threads = 8 waves, all covering the SAME 256 pixels.
// wave wv: kq = wv>>1 reduces ci in [60kq, 60kq+60); ch = wv&1 computes
// output channels [12ch, 12ch+12). Lane owns a 4-pixel quad.
// -> acc = 48 regs/thread, ~110 VGPR total: no spills under the 128-reg cap,
//    and 392 blocks x 8 waves = 3136 waves = 3 waves/SIMD TLP.
// x loads double-buffered in 5-ci chunks (5 float4 in flight per buffer).
__global__ __launch_bounds__(512, 4) void conv1x1_kernel(
    const float* __restrict__ x, const float* __restrict__ wt,
    const float* __restrict__ bias1, float* __restrict__ out) {
  __shared__ float smem[6144];   // [0,5760) weights; aliased by red[2][48][64]
  const int tid  = threadIdx.x;
  const int lane = tid & 63;
  const int wv   = tid >> 6;     // 0..7
  const int kq   = wv >> 1;      // K-chunk 0..3
  const int ch   = wv & 1;       // co-half 0..1

  for (int i = tid; i < 5760; i += 512) smem[i] = wt[i];
  __syncthreads();

  const int P  = blockIdx.x * 256 + lane * 4;  // quad base pixel
  const int b  = P / HW;                       // quads never cross batches
  const int hw = P - b * HW;
  const int ci0 = kq * 60;
  const float* xp    = x + ((size_t)b * CIN + ci0) * HW + hw;
  const float* wbase = smem + ci0 * C1 + ch * 12;

  float acc[48];                 // acc[co*4 + px], co in [0,12)
#pragma unroll
  for (int i = 0; i < 48; ++i) acc[i] = 0.f;

  float4 A[5], B[5];
#pragma unroll
  for (int j = 0; j < 5; ++j) A[j] = *(const float4*)(xp + (size_t)j * HW);
#pragma unroll
  for (int j = 0; j < 5; ++j) B[j] = *(const float4*)(xp + (size_t)(5 + j) * HW);

  auto consume = [&](const float4* buf, int cb) {
#pragma unroll
    for (int j = 0; j < 5; ++j) {
      const float4 xv = buf[j];
      const float* wr = wbase + (cb + j) * C1;
#pragma unroll
      for (int k = 0; k < 3; ++k) {
        const float4 wq = *(const float4*)(wr + 4 * k);
        const int o = 16 * k;
        acc[o+ 0] = fmaf(wq.x, xv.x, acc[o+ 0]);
        acc[o+ 1] = fmaf(wq.x, xv.y, acc[o+ 1]);
        acc[o+ 2] = fmaf(wq.x, xv.z, acc[o+ 2]);
        acc[o+ 3] = fmaf(wq.x, xv.w, acc[o+ 3]);
        acc[o+ 4] = fmaf(wq.y, xv.x, acc[o+ 4]);
        acc[o+ 5] = fmaf(wq.y, xv.y, acc[o+ 5]);
        acc[o+ 6] = fmaf(wq.y, xv.z, acc[o+ 6]);
        acc[o+ 7] = fmaf(wq.y, xv.w, acc[o+ 7]);
        acc[o+ 8] = fmaf(wq.z, xv.x, acc[o+ 8]);
        acc[o+ 9] = fmaf(wq.z, xv.y, acc[o+ 9]);
        acc[o+10] = fmaf(wq.z, xv.z, acc[o+10]);
        acc[o+11] = fmaf(wq.z, xv.w, acc[o+11]);
        acc[o+12] = fmaf(wq.w, xv.x, acc[o+12]);
        acc[o+13] = fmaf(wq.w, xv.y, acc[o+13]);
        acc[o+14] = fmaf(wq.w, xv.z, acc[o+14]);
        acc[o+15] = fmaf(wq.w, xv.w, acc[o+15]);
      }
    }
  };

#pragma unroll 1
  for (int g = 0; g < 5; ++g) {
    const int c = 10 * g;
    consume(A, c);
#pragma unroll
    for (int j = 0; j < 5; ++j)
      A[j] = *(const float4*)(xp + (size_t)(c + 10 + j) * HW);
    consume(B, c + 5);
#pragma unroll
    for (int j = 0; j < 5; ++j)
      B[j] = *(const float4*)(xp + (size_t)(c + 15 + j) * HW);
  }
  consume(A, 50);
  consume(B, 55);
  __syncthreads();               // weights dead; smem -> reduction buffers

  float* red = smem + ch * 3072; // [48][64] per co-half; stride-64 = 2-way free

  // reduce kq 3 -> 1, 2 -> 0, 1 -> 0 (sequential rounds, one buffer)
  if (kq == 3) {
#pragma unroll
    for (int i = 0; i < 48; ++i) red[i * 64 + lane] = acc[i];
  }
  __syncthreads();
  if (kq == 1) {
#pragma unroll
    for (int i = 0; i < 48; ++i) acc[i] += red[i * 64 + lane];
  }
  __syncthreads();
  if (kq == 2) {
#pragma unroll
    for (int i = 0; i < 48; ++i) red[i * 64 + lane] = acc[i];
  }
  __syncthreads();
  if (kq == 0) {
#pragma unroll
    for (int i = 0; i < 48; ++i) acc[i] += red[i * 64 + lane];
  }
  __syncthreads();
  if (kq == 1) {
#pragma unroll
    for (int i = 0; i < 48; ++i) red[i * 64 + lane] = acc[i];
  }
  __syncthreads();
  if (kq == 0) {
    float* o = out + ((size_t)b * COUT + C1 + ch * 12) * HW + hw;
#pragma unroll
    for (int co = 0; co < 12; ++co) {
      const float bb = bias1[ch * 12 + co];
      float4 v;
      v.x = acc[co*4+0] + red[(co*4+0)*64 + lane] + bb;
      v.y = acc[co*4+1] + red[(co*4+1)*64 + lane] + bb;
      v.z = acc[co*4+2] + red[(co*4+2)*64 + lane] + bb;
      v.w = acc[co*4+3] + red[(co*4+3)*64 + lane] + bb;
      *(float4*)(o + (size_t)co * HW) = v;
    }
  }
}

// depthwise 3x3 conv + BN2: reads t1 from out ch [24,48), writes x1 to ch [0,24).
// Thread = 4-pixel quad; zero-substitution at borders is exact (w * 0 == 0).
__global__ __launch_bounds__(256) void dw_kernel(
    const float* __restrict__ outr, const float* __restrict__ wdwf,
    const float* __restrict__ bias2, float* __restrict__ out) {
  const int c = blockIdx.y, b = blockIdx.z;
  const int q = blockIdx.x * 256 + threadIdx.x;   // quad id in [0,784)
  if (q >= 784) return;
  const int h  = q / 14;
  const int w0 = (q - h * 14) * 4;
  const float* in = outr + ((size_t)b * COUT + C1 + c) * HW;

  float wk[9];
#pragma unroll
  for (int k = 0; k < 9; ++k) wk[k] = wdwf[c * 9 + k];   // uniform -> scalar
  const float bb = bias2[c];

  float xr[3][6];
#pragma unroll
  for (int kh = 0; kh < 3; ++kh) {
    const int hh = h + kh - 1;
    const bool rok = (hh >= 0) & (hh < H_);
    const float* rp = in + hh * W_;
    xr[kh][0] = (rok && w0 > 0) ? rp[w0 - 1] : 0.f;
    if (rok) {
      const float4 m = *(const float4*)(rp + w0);
      xr[kh][1] = m.x; xr[kh][2] = m.y; xr[kh][3] = m.z; xr[kh][4] = m.w;
    } else {
      xr[kh][1] = 0.f; xr[kh][2] = 0.f; xr[kh][3] = 0.f; xr[kh][4] = 0.f;
    }
    xr[kh][5] = (rok && w0 < W_ - 4) ? rp[w0 + 4] : 0.f;
  }

  float4 v = {bb, bb, bb, bb};
#pragma unroll
  for (int kh = 0; kh < 3; ++kh) {
#pragma unroll
    for (int kw = 0; kw < 3; ++kw) {
      const float t = wk[kh * 3 + kw];
      v.x = fmaf(xr[kh][kw + 0], t, v.x);
      v.y = fmaf(xr[kh][kw + 1], t, v.y);
      v.z = fmaf(xr[kh][kw + 2], t, v.z);
      v.w = fmaf(xr[kh][kw + 3], t, v.w);
    }
  }
  *(float4*)(out + ((size_t)b * COUT + c) * HW + h * W_ + w0) = v;
}

// adder depthwise (24 -> 216) + BN3 + ReLU: reads x1 from out ch [0,24),
// writes x2 to out ch [24,240). Thread = 4-pixel quad, all 9 r-channels.
// Reference pads x1 with zeros and still takes |0 - tap| at borders, so OOB
// positions contribute fabsf(tap) -- we substitute 0, never skip taps.
__global__ __launch_bounds__(256) void adder_kernel(
    const float* __restrict__ outr, const float* __restrict__ wadd,
    const float* __restrict__ inv3, const float* __restrict__ t3,
    float* __restrict__ out) {
  const int c = blockIdx.y, b = blockIdx.z;
  __shared__ float taps[R_][3][4];   // [r][kh][kw, padded to 4]
  __shared__ float s3[R_], t3s[R_];
  const int tid = threadIdx.x;
  if (tid < 108) {
    int r = tid / 12, kh = (tid / 4) % 3, kw = tid & 3;
    taps[r][kh][kw] = (kw < 3) ? wadd[((c * R_ + r) * 3 + kh) * 3 + kw] : 0.f;
  } else if (tid >= 128 && tid < 128 + R_) {
    int r = tid - 128;
    s3[r]  = inv3[c * R_ + r];
    t3s[r] = t3[c * R_ + r];
  }
  __syncthreads();

  const int q = blockIdx.x * 256 + tid;   // pixel quad id in [0,784)
  if (q >= 784) return;
  const int h  = q / 14;
  const int w0 = (q - h * 14) * 4;
  const float* in = outr + ((size_t)b * COUT + c) * HW;

  float xr[3][6];
#pragma unroll
  for (int kh = 0; kh < 3; ++kh) {
    const int hh = h + kh - 1;
    const bool rok = (hh >= 0) & (hh < H_);
    const float* rp = in + hh * W_;
    xr[kh][0] = (rok && w0 > 0) ? rp[w0 - 1] : 0.f;
    if (rok) {
      const float4 m = *(const float4*)(rp + w0);
      xr[kh][1] = m.x; xr[kh][2] = m.y; xr[kh][3] = m.z; xr[kh][4] = m.w;
    } else {
      xr[kh][1] = 0.f; xr[kh][2] = 0.f; xr[kh][3] = 0.f; xr[kh][4] = 0.f;
    }
    xr[kh][5] = (rok && w0 < W_ - 4) ? rp[w0 + 4] : 0.f;
  }

#pragma unroll
  for (int r = 0; r < R_; ++r) {
    float a0 = 0.f, a1 = 0.f, a2 = 0.f, a3 = 0.f;
#pragma unroll
    for (int kh = 0; kh < 3; ++kh) {
#pragma unroll
      for (int kw = 0; kw < 3; ++kw) {
        const float t = taps[r][kh][kw];
        a0 += fabsf(xr[kh][kw + 0] - t);
        a1 += fabsf(xr[kh][kw + 1] - t);
        a2 += fabsf(xr[kh][kw + 2] - t);
        a3 += fabsf(xr[kh][kw + 3] - t);
      }
    }
    const float s = s3[r], bb = t3s[r];
    float4 v;
    v.x = fmaxf(fmaf(-s, a0, bb), 0.f);
    v.y = fmaxf(fmaf(-s, a1, bb), 0.f);
    v.z = fmaxf(fmaf(-s, a2, bb), 0.f);
    v.w = fmaxf(fmaf(-s, a3, bb), 0.f);
    *(float4*)(out + ((size_t)b * COUT + C1 + c * R_ + r) * HW + h * W_ + w0) = v;
  }
}

extern "C" void kernel_launch(void* const* d_in, const int* in_sizes, int n_in,
                              void* d_out, int out_size, void* d_ws, size_t ws_size,
                              hipStream_t stream) {
  const float* x    = (const float*)d_in[0];
  const float* wp   = (const float*)d_in[1];
  const float* g1   = (const float*)d_in[2];
  const float* b1   = (const float*)d_in[3];
  const float* m1   = (const float*)d_in[4];
  const float* v1   = (const float*)d_in[5];
  const float* wdw  = (const float*)d_in[6];
  const float* g2   = (const float*)d_in[7];
  const float* b2   = (const float*)d_in[8];
  const float* m2   = (const float*)d_in[9];
  const float* v2   = (const float*)d_in[10];
  const float* wadd = (const float*)d_in[11];
  const float* g3   = (const float*)d_in[12];
  const float* b3   = (const float*)d_in[13];
  const float* m3   = (const float*)d_in[14];
  const float* v3   = (const float*)d_in[15];

  float* ws  = (float*)d_ws;
  float* out = (float*)d_out;

  // fold BN params / transpose weights (~26 KB of ws)
  prep_kernel<<<25, 256, 0, stream>>>(wp, g1, b1, m1, v1, wdw, g2, b2, m2, v2,
                                      g3, b3, m3, v3, ws);

  // 1x1 conv + BN1 -> t1 in out channels [24,48). 392 blocks x 256 px x 8 waves.
  conv1x1_kernel<<<392, 512, 0, stream>>>(x, ws + WS_WT, ws + WS_B1, out);

  // dw 3x3 + BN2: t1 (ch 24..47) -> x1 (ch 0..23)
  dw_kernel<<<dim3(4, C1, BATCH), 256, 0, stream>>>(out, ws + WS_WDW,
                                                    ws + WS_B2, out);

  // adder + BN3 + ReLU: x1 (ch 0..23) -> x2 (ch 24..239)
  adder_kernel<<<dim3(4, C1, BATCH), 256, 0, stream>>>(out, wadd, ws + WS_INV3,
                                                       ws + WS_T3, out);
}

// Round 6
// 217.646 us; speedup vs baseline: 1.1108x; 1.1108x over previous
//
#include <hip/hip_runtime.h>

#define EPS_ 1e-5f
#define BATCH 32
#define CIN 240
#define H_ 56
#define W_ 56
#define HW 3136          // 56*56
#define C1 24            // init_c
#define R_ 9             // ratio-1
#define C2 216           // C1*R_
#define COUT 240

// ---- workspace layout (floats) ---- total 6464 floats (~26 KB)
#define WS_WT   0        // [240][24]  conv1x1 weights, ci-major, BN1 scale folded
#define WS_B1   5760     // [24]       BN1 bias
#define WS_WDW  5784     // [24][9]    dw weights, BN2 scale folded
#define WS_B2   6000     // [24]       BN2 bias
#define WS_INV3 6024     // [216]
#define WS_T3   6240     // [216]
// t1 (conv1x1+BN1 intermediate) lives in OUT channels [24,48) until the adder
// kernel overwrites them (stream-ordered; every kernel's read set is disjoint
// from its own write set).

__global__ __launch_bounds__(256) void prep_kernel(
    const float* __restrict__ wp,
    const float* __restrict__ g1, const float* __restrict__ b1,
    const float* __restrict__ m1, const float* __restrict__ v1,
    const float* __restrict__ wdw,
    const float* __restrict__ g2, const float* __restrict__ b2,
    const float* __restrict__ m2, const float* __restrict__ v2,
    const float* __restrict__ g3, const float* __restrict__ b3,
    const float* __restrict__ m3, const float* __restrict__ v3,
    float* __restrict__ ws) {
  int i = blockIdx.x * 256 + threadIdx.x;
  if (i < 5760) {
    // transpose w_primary (co-major [24][240]) -> ci-major [240][24], fold BN1
    int ci = i / C1, co = i % C1;
    float s = g1[co] / sqrtf(v1[co] + EPS_);
    ws[WS_WT + ci * C1 + co] = wp[co * CIN + ci] * s;
    if (ci == 0) ws[WS_B1 + co] = b1[co] - m1[co] * s;
  } else if (i < 5760 + C2) {
    int j = i - 5760;           // [0,216): c*9+k
    int c = j / 9;
    float s = g2[c] / sqrtf(v2[c] + EPS_);
    ws[WS_WDW + j] = wdw[j] * s;
    if (j % 9 == 0) ws[WS_B2 + c] = b2[c] - m2[c] * s;
  } else if (i < 5976 + C2) {
    int j = i - 5976;           // [0,216)
    float s = g3[j] / sqrtf(v3[j] + EPS_);
    ws[WS_INV3 + j] = s;
    ws[WS_T3 + j] = b3[j] - m3[j] * s;
  }
}

// 1x1 conv (240 -> 24) + BN1 -> out channels [24,48).
// Block = 256 threads = 4 waves over the SAME 64 pixels; lane = 1 pixel.
// Wave kq reduces ci in [60kq, 60kq+60); acc[24] per thread (~70 VGPR total,
// no launch-bounds cap -> no spills; 1568 blocks x 4 waves = 6 waves/SIMD).
// Weights in LDS (broadcast b128, conflict-free); x double-buffered in 6-ci
// chunks (6 independent loads in flight). Cross-wave reduce: all 4 waves dump
// acc into LDS (aliased over dead weights), each wave finishes 6 channels.
__global__ __launch_bounds__(256) void conv1x1_kernel(
    const float* __restrict__ x, const float* __restrict__ wt,
    const float* __restrict__ bias1, float* __restrict__ out) {
  __shared__ float smem[6144];   // [0,5760) weights; then red[4][24][64]
  const int tid  = threadIdx.x;
  const int lane = tid & 63;
  const int kq   = tid >> 6;     // K-chunk 0..3

  for (int i = tid; i < 5760; i += 256) smem[i] = wt[i];
  __syncthreads();

  const int P   = blockIdx.x * 64 + lane;   // global pixel; 49 blocks/batch
  const int b   = P / HW;
  const int hw  = P - b * HW;
  const int ci0 = kq * 60;
  const float* xp    = x + ((size_t)b * CIN + ci0) * HW + hw;
  const float* wbase = smem + ci0 * C1;

  float acc[C1];
#pragma unroll
  for (int i = 0; i < C1; ++i) acc[i] = 0.f;

  float A[6], B[6];
#pragma unroll
  for (int j = 0; j < 6; ++j) A[j] = xp[(size_t)j * HW];
#pragma unroll
  for (int j = 0; j < 6; ++j) B[j] = xp[(size_t)(6 + j) * HW];

  auto consume = [&](const float* buf, int cb) {
#pragma unroll
    for (int j = 0; j < 6; ++j) {
      const float xv = buf[j];
      const float* wr = wbase + (cb + j) * C1;
#pragma unroll
      for (int k = 0; k < 6; ++k) {
        const float4 wq = *(const float4*)(wr + 4 * k);
        acc[4*k+0] = fmaf(wq.x, xv, acc[4*k+0]);
        acc[4*k+1] = fmaf(wq.y, xv, acc[4*k+1]);
        acc[4*k+2] = fmaf(wq.z, xv, acc[4*k+2]);
        acc[4*k+3] = fmaf(wq.w, xv, acc[4*k+3]);
      }
    }
  };

#pragma unroll 1
  for (int g = 0; g < 4; ++g) {
    const int c = 12 * g;
    consume(A, c);
#pragma unroll
    for (int j = 0; j < 6; ++j) A[j] = xp[(size_t)(c + 12 + j) * HW];
    consume(B, c + 6);
#pragma unroll
    for (int j = 0; j < 6; ++j) B[j] = xp[(size_t)(c + 18 + j) * HW];
  }
  consume(A, 48);
  consume(B, 54);
  __syncthreads();               // weights dead; smem -> red[4][24][64]

#pragma unroll
  for (int i = 0; i < C1; ++i) smem[(kq * C1 + i) * 64 + lane] = acc[i];
  __syncthreads();

  // wave kq finishes channels [6kq, 6kq+6)
  float* o = out + ((size_t)b * COUT + C1) * HW + hw;
#pragma unroll
  for (int i = 0; i < 6; ++i) {
    const int co = kq * 6 + i;
    float v = smem[(0 * C1 + co) * 64 + lane]
            + smem[(1 * C1 + co) * 64 + lane]
            + smem[(2 * C1 + co) * 64 + lane]
            + smem[(3 * C1 + co) * 64 + lane]
            + bias1[co];
    o[(size_t)co * HW] = v;
  }
}

// depthwise 3x3 conv + BN2: reads t1 from out ch [24,48), writes x1 to ch [0,24).
// Thread = 4-pixel quad; zero-substitution at borders is exact (w * 0 == 0).
__global__ __launch_bounds__(256) void dw_kernel(
    const float* __restrict__ outr, const float* __restrict__ wdwf,
    const float* __restrict__ bias2, float* __restrict__ out) {
  const int c = blockIdx.y, b = blockIdx.z;
  const int q = blockIdx.x * 256 + threadIdx.x;   // quad id in [0,784)
  if (q >= 784) return;
  const int h  = q / 14;
  const int w0 = (q - h * 14) * 4;
  const float* in = outr + ((size_t)b * COUT + C1 + c) * HW;

  float wk[9];
#pragma unroll
  for (int k = 0; k < 9; ++k) wk[k] = wdwf[c * 9 + k];   // uniform -> scalar
  const float bb = bias2[c];

  float xr[3][6];
#pragma unroll
  for (int kh = 0; kh < 3; ++kh) {
    const int hh = h + kh - 1;
    const bool rok = (hh >= 0) & (hh < H_);
    const float* rp = in + hh * W_;
    xr[kh][0] = (rok && w0 > 0) ? rp[w0 - 1] : 0.f;
    if (rok) {
      const float4 m = *(const float4*)(rp + w0);
      xr[kh][1] = m.x; xr[kh][2] = m.y; xr[kh][3] = m.z; xr[kh][4] = m.w;
    } else {
      xr[kh][1] = 0.f; xr[kh][2] = 0.f; xr[kh][3] = 0.f; xr[kh][4] = 0.f;
    }
    xr[kh][5] = (rok && w0 < W_ - 4) ? rp[w0 + 4] : 0.f;
  }

  float4 v = {bb, bb, bb, bb};
#pragma unroll
  for (int kh = 0; kh < 3; ++kh) {
#pragma unroll
    for (int kw = 0; kw < 3; ++kw) {
      const float t = wk[kh * 3 + kw];
      v.x = fmaf(xr[kh][kw + 0], t, v.x);
      v.y = fmaf(xr[kh][kw + 1], t, v.y);
      v.z = fmaf(xr[kh][kw + 2], t, v.z);
      v.w = fmaf(xr[kh][kw + 3], t, v.w);
    }
  }
  *(float4*)(out + ((size_t)b * COUT + c) * HW + h * W_ + w0) = v;
}

// adder depthwise (24 -> 216) + BN3 + ReLU: reads x1 from out ch [0,24),
// writes x2 to out ch [24,240). Thread = 4-pixel quad, all 9 r-channels.
// Reference pads x1 with zeros and still takes |0 - tap| at borders, so OOB
// positions contribute fabsf(tap) -- we substitute 0, never skip taps.
__global__ __launch_bounds__(256) void adder_kernel(
    const float* __restrict__ outr, const float* __restrict__ wadd,
    const float* __restrict__ inv3, const float* __restrict__ t3,
    float* __restrict__ out) {
  const int c = blockIdx.y, b = blockIdx.z;
  __shared__ float taps[R_][3][4];   // [r][kh][kw, padded to 4]
  __shared__ float s3[R_], t3s[R_];
  const int tid = threadIdx.x;
  if (tid < 108) {
    int r = tid / 12, kh = (tid / 4) % 3, kw = tid & 3;
    taps[r][kh][kw] = (kw < 3) ? wadd[((c * R_ + r) * 3 + kh) * 3 + kw] : 0.f;
  } else if (tid >= 128 && tid < 128 + R_) {
    int r = tid - 128;
    s3[r]  = inv3[c * R_ + r];
    t3s[r] = t3[c * R_ + r];
  }
  __syncthreads();

  const int q = blockIdx.x * 256 + tid;   // pixel quad id in [0,784)
  if (q >= 784) return;
  const int h  = q / 14;
  const int w0 = (q - h * 14) * 4;
  const float* in = outr + ((size_t)b * COUT + c) * HW;

  float xr[3][6];
#pragma unroll
  for (int kh = 0; kh < 3; ++kh) {
    const int hh = h + kh - 1;
    const bool rok = (hh >= 0) & (hh < H_);
    const float* rp = in + hh * W_;
    xr[kh][0] = (rok && w0 > 0) ? rp[w0 - 1] : 0.f;
    if (rok) {
      const float4 m = *(const float4*)(rp + w0);
      xr[kh][1] = m.x; xr[kh][2] = m.y; xr[kh][3] = m.z; xr[kh][4] = m.w;
    } else {
      xr[kh][1] = 0.f; xr[kh][2] = 0.f; xr[kh][3] = 0.f; xr[kh][4] = 0.f;
    }
    xr[kh][5] = (rok && w0 < W_ - 4) ? rp[w0 + 4] : 0.f;
  }

#pragma unroll
  for (int r = 0; r < R_; ++r) {
    float a0 = 0.f, a1 = 0.f, a2 = 0.f, a3 = 0.f;
#pragma unroll
    for (int kh = 0; kh < 3; ++kh) {
#pragma unroll
      for (int kw = 0; kw < 3; ++kw) {
        const float t = taps[r][kh][kw];
        a0 += fabsf(xr[kh][kw + 0] - t);
        a1 += fabsf(xr[kh][kw + 1] - t);
        a2 += fabsf(xr[kh][kw + 2] - t);
        a3 += fabsf(xr[kh][kw + 3] - t);
      }
    }
    const float s = s3[r], bb = t3s[r];
    float4 v;
    v.x = fmaxf(fmaf(-s, a0, bb), 0.f);
    v.y = fmaxf(fmaf(-s, a1, bb), 0.f);
    v.z = fmaxf(fmaf(-s, a2, bb), 0.f);
    v.w = fmaxf(fmaf(-s, a3, bb), 0.f);
    *(float4*)(out + ((size_t)b * COUT + C1 + c * R_ + r) * HW + h * W_ + w0) = v;
  }
}

extern "C" void kernel_launch(void* const* d_in, const int* in_sizes, int n_in,
                              void* d_out, int out_size, void* d_ws, size_t ws_size,
                              hipStream_t stream) {
  const float* x    = (const float*)d_in[0];
  const float* wp   = (const float*)d_in[1];
  const float* g1   = (const float*)d_in[2];
  const float* b1   = (const float*)d_in[3];
  const float* m1   = (const float*)d_in[4];
  const float* v1   = (const float*)d_in[5];
  const float* wdw  = (const float*)d_in[6];
  const float* g2   = (const float*)d_in[7];
  const float* b2   = (const float*)d_in[8];
  const float* m2   = (const float*)d_in[9];
  const float* v2   = (const float*)d_in[10];
  const float* wadd = (const float*)d_in[11];
  const float* g3   = (const float*)d_in[12];
  const float* b3   = (const float*)d_in[13];
  const float* m3   = (const float*)d_in[14];
  const float* v3   = (const float*)d_in[15];

  float* ws  = (float*)d_ws;
  float* out = (float*)d_out;

  // fold BN params / transpose weights (~26 KB of ws)
  prep_kernel<<<25, 256, 0, stream>>>(wp, g1, b1, m1, v1, wdw, g2, b2, m2, v2,
                                      g3, b3, m3, v3, ws);

  // 1x1 conv + BN1 -> t1 in out channels [24,48). 1568 blocks x 64 px x 4 waves.
  conv1x1_kernel<<<1568, 256, 0, stream>>>(x, ws + WS_WT, ws + WS_B1, out);

  // dw 3x3 + BN2: t1 (ch 24..47) -> x1 (ch 0..23)
  dw_kernel<<<dim3(4, C1, BATCH), 256, 0, stream>>>(out, ws + WS_WDW,
                                                    ws + WS_B2, out);

  // adder + BN3 + ReLU: x1 (ch 0..23) -> x2 (ch 24..239)
  adder_kernel<<<dim3(4, C1, BATCH), 256, 0, stream>>>(out, wadd, ws + WS_INV3,
                                                       ws + WS_T3, out);
}